// Round 7
// baseline (433.782 us; speedup 1.0000x reference)
//
#include <hip/hip_runtime.h>
#include <hip/hip_bf16.h>

// MHAHead B=8,S=2048,E=512. R7 = R6 with two fixes:
//  (1) gemmS rowsum: shfl butterfly now runs under full exec (R6 ran it inside
//      a divergent if -> garbage partners -> wrong denominators).
//  (2) store_tile_bf16: __syncthreads() between LDS write/read phases (R6 was
//      a formal cross-lane race the compiler may reorder).

typedef unsigned short u16;
typedef unsigned int u32;
typedef __attribute__((ext_vector_type(8))) short short8;
typedef __attribute__((ext_vector_type(4))) float float4v;

#define S_DIM 2048
#define E_DIM 512
#define NROWS (8 * S_DIM)
#define SCALE 0.044194173824159216f
#define WB_W_U16 (3 * 262144)
#define WB_B_U16 (3 * 512)
#define FLAG_BYTE ((WB_W_U16 + WB_B_U16) * 2)

__device__ __forceinline__ float4v mfma16(short8 a, short8 b, float4v c) {
    return __builtin_amdgcn_mfma_f32_16x16x32_bf16(a, b, c, 0, 0, 0);
}
__device__ __forceinline__ float bf2f(unsigned int u) {
    union { unsigned int i; float f; } v; v.i = u << 16; return v.f;
}
__device__ __forceinline__ u16 f2bf_bits(float f) {
    __hip_bfloat16 h = __float2bfloat16(f);
    return *(u16*)&h;
}
__device__ __forceinline__ int detect_bf16(const void* wp) {
    const u16* w = (const u16*)wp;
    int cnt = 0;
    for (int i = 0; i < 64; ++i) {
        int e = (w[2 * i] >> 7) & 0xff;
        cnt += (e >= 100 && e <= 131) ? 1 : 0;
    }
    return cnt >= 40;
}
__device__ __forceinline__ void load8(const void* base, size_t idx, int isbf, float* f) {
    if (isbf) {
        uint4 v = *(const uint4*)((const u16*)base + idx);
        f[0] = bf2f(v.x & 0xffffu); f[1] = bf2f(v.x >> 16);
        f[2] = bf2f(v.y & 0xffffu); f[3] = bf2f(v.y >> 16);
        f[4] = bf2f(v.z & 0xffffu); f[5] = bf2f(v.z >> 16);
        f[6] = bf2f(v.w & 0xffffu); f[7] = bf2f(v.w >> 16);
    } else {
        const float* p = (const float*)base + idx;
        float4 a = *(const float4*)p;
        float4 b = *(const float4*)(p + 4);
        f[0] = a.x; f[1] = a.y; f[2] = a.z; f[3] = a.w;
        f[4] = b.x; f[5] = b.y; f[6] = b.z; f[7] = b.w;
    }
}
__device__ __forceinline__ float load1(const void* base, size_t idx, int isbf) {
    return isbf ? bf2f(((const u16*)base)[idx]) : ((const float*)base)[idx];
}
__device__ __forceinline__ void gld16(const u16* g, u16* l) {
    __builtin_amdgcn_global_load_lds(
        (const __attribute__((address_space(1))) void*)g,
        (__attribute__((address_space(3))) void*)l, 16, 0, 0);
}

// ---------------- conv_w: weights+biases -> bf16 in ws, + dtype flag --------
__global__ __launch_bounds__(256) void conv_w(
    const void* w0, const void* w1, const void* w2,
    const void* b0, const void* b1, const void* b2, u16* wb)
{
    const int z = blockIdx.y;
    const void* w = (z == 0) ? w0 : (z == 1) ? w1 : w2;
    const void* bb = (z == 0) ? b0 : (z == 1) ? b1 : b2;
    const int isbf = detect_bf16(w0);
    const size_t idx = ((size_t)blockIdx.x * 256 + threadIdx.x) * 8;
    float f[8];
    load8(w, idx, isbf, f);
    union { u16 h[8]; uint4 v; } pk;
#pragma unroll
    for (int j = 0; j < 8; ++j) pk.h[j] = f2bf_bits(f[j]);
    *(uint4*)(wb + (size_t)z * 262144 + idx) = pk.v;
    if (blockIdx.x == 0) {
        u16* bbase = wb + WB_W_U16 + z * 512;
#pragma unroll
        for (int j = 0; j < 2; ++j) {
            int i = threadIdx.x * 2 + j;
            bbase[i] = f2bf_bits(load1(bb, i, isbf));
        }
        if (z == 0 && threadIdx.x == 0)
            *(int*)((char*)wb + FLAG_BYTE) = isbf;
    }
}

// ---------------- conv_x: x fp32 -> bf16 lead halves ----------------
__global__ __launch_bounds__(256) void conv_x(void* xbuf, const int* flagp) {
    if (*flagp) return;                          // already bf16 (stride 512)
    const int w = threadIdx.x >> 6, l = threadIdx.x & 63;
    const int row = blockIdx.x * 4 + w;
    const float* src = (const float*)xbuf + (size_t)row * E_DIM + l * 8;
    float4 a = *(const float4*)src;
    float4 b = *(const float4*)(src + 4);
    union { u16 h[8]; uint4 v; } pk;
    pk.h[0] = f2bf_bits(a.x); pk.h[1] = f2bf_bits(a.y);
    pk.h[2] = f2bf_bits(a.z); pk.h[3] = f2bf_bits(a.w);
    pk.h[4] = f2bf_bits(b.x); pk.h[5] = f2bf_bits(b.y);
    pk.h[6] = f2bf_bits(b.z); pk.h[7] = f2bf_bits(b.w);
    *(uint4*)((u16*)xbuf + (size_t)row * 1024 + l * 8) = pk.v;
}

// ---------------- mask_compress: int32 -> bitmask (1 = masked) --------------
__global__ __launch_bounds__(256) void mask_compress(
    const int* __restrict__ mask, u32* __restrict__ bits,
    int mode, const int* flagp)
{
    if (mode == 1 && *flagp) return;             // no valid destination
    const size_t widx = (size_t)blockIdx.x * 256 + threadIdx.x;
    const int* src = mask + widx * 32;
    u32 v = 0;
#pragma unroll
    for (int j = 0; j < 32; j += 4) {
        int4 m4 = *(const int4*)(src + j);
        v |= (u32)(m4.x > 0) << j;
        v |= (u32)(m4.y > 0) << (j + 1);
        v |= (u32)(m4.z > 0) << (j + 2);
        v |= (u32)(m4.w > 0) << (j + 3);
    }
    bits[widx] = v;
}

// ---------------- GEMM core: 128x128xBK32, m97 2-barrier loop ---------------
__device__ __forceinline__ void gemm_core(
    const u16* __restrict__ A, int sA, const u16* __restrict__ B, int sB, int K,
    u16* As, u16* Bs, float4v acc[4][4])
{
    const int t = threadIdx.x;
    const int w = t >> 6, l = t & 63;
    const int lane15 = l & 15, quad = l >> 4;
    const int wm = w & 1, wn = w >> 1;

    for (int kt = 0; kt < K; kt += 32) {
        __syncthreads();
#pragma unroll
        for (int i = 0; i < 2; ++i) {
            const int fg = w * 128 + i * 64 + l;
            const int r = fg >> 2;
            const int kq = (fg & 3) ^ ((r >> 1) & 3);
            gld16(A + (size_t)r * sA + kt + kq * 8, As + fg * 8);
            gld16(B + (size_t)r * sB + kt + kq * 8, Bs + fg * 8);
        }
        __syncthreads();

        short8 af[4], bf[4];
#pragma unroll
        for (int mi = 0; mi < 4; ++mi) {
            const int r = wm * 64 + mi * 16 + lane15;
            af[mi] = *(const short8*)&As[(4 * r + (quad ^ ((r >> 1) & 3))) * 8];
        }
#pragma unroll
        for (int ni = 0; ni < 4; ++ni) {
            const int r = wn * 64 + ni * 16 + lane15;
            bf[ni] = *(const short8*)&Bs[(4 * r + (quad ^ ((r >> 1) & 3))) * 8];
        }
#pragma unroll
        for (int mi = 0; mi < 4; ++mi)
#pragma unroll
            for (int ni = 0; ni < 4; ++ni)
                acc[mi][ni] = mfma16(af[mi], bf[ni], acc[mi][ni]);
    }
}

// per-wave LDS redistribution: column strips -> row chunks, coalesced stores.
// Block-wide barriers make the cross-lane LDS traffic race-free. All call
// sites are block-uniform.
__device__ __forceinline__ void store_tile_bf16(
    u16 (*Ts)[40], const u16 vals[4][4][4],
    int lane15, int quad, u16* gbase, size_t rstride)
{
#pragma unroll
    for (int h = 0; h < 2; ++h) {
#pragma unroll
        for (int mi = 0; mi < 4; ++mi)
#pragma unroll
            for (int nn = 0; nn < 2; ++nn)
#pragma unroll
                for (int r = 0; r < 4; ++r)
                    Ts[mi * 16 + quad * 4 + r][nn * 16 + lane15] =
                        vals[mi][2 * h + nn][r];
        __syncthreads();
#pragma unroll
        for (int mi = 0; mi < 4; ++mi) {
            uint4 v = *(const uint4*)&Ts[mi * 16 + lane15][quad * 8];
            *(uint4*)(gbase + (size_t)(mi * 16 + lane15) * rstride +
                      h * 32 + quad * 8) = v;
        }
        __syncthreads();
    }
}

#define GEMM_IDS()                                                  \
    const int t = threadIdx.x;                                      \
    const int w = t >> 6, l = t & 63; (void)l;                      \
    const int lane15 = l & 15, quad = l >> 4;                       \
    const int wm = w & 1, wn = w >> 1;

// ---------------- proj: Q, K, Vt ----------------
__global__ __launch_bounds__(256) void proj_gemm(
    const void* __restrict__ xorig, const int* flagp,
    const u16* __restrict__ wb,
    u16* __restrict__ qb, u16* __restrict__ kb, int sQK, u16* __restrict__ vt)
{
    __shared__ u16 As[4096] __attribute__((aligned(16)));
    __shared__ u16 Bs[4096] __attribute__((aligned(16)));
    __shared__ u16 Ts[4][64][40];
    GEMM_IDS();

    const int z = blockIdx.z;
    const int isbf = *(const volatile int*)flagp;
    const u16* xb = (const u16*)xorig;
    const int sx = isbf ? 512 : 1024;
    const u16* bias = wb + WB_W_U16 + z * 512;

    int m0, n0; const u16 *A, *B; int sA, sB;
    if (z < 2) {
        m0 = blockIdx.y * 128; n0 = blockIdx.x * 128;
        A = xb + (size_t)m0 * sx; sA = sx;
        B = wb + (size_t)z * 262144 + (size_t)n0 * 512; sB = 512;
    } else {
        m0 = blockIdx.x * 128; n0 = blockIdx.y * 128;
        A = wb + (size_t)2 * 262144 + (size_t)m0 * 512; sA = 512;
        B = xb + (size_t)n0 * sx; sB = sx;
    }

    float bcol[4], brow[4][4];
    if (z < 2) {
#pragma unroll
        for (int ni = 0; ni < 4; ++ni)
            bcol[ni] = bf2f(bias[n0 + wn * 64 + ni * 16 + lane15]);
    } else {
#pragma unroll
        for (int mi = 0; mi < 4; ++mi)
#pragma unroll
            for (int r = 0; r < 4; ++r)
                brow[mi][r] = bf2f(bias[m0 + wm * 64 + mi * 16 + quad * 4 + r]);
    }

    float4v acc[4][4];
#pragma unroll
    for (int mi = 0; mi < 4; ++mi)
#pragma unroll
        for (int ni = 0; ni < 4; ++ni) acc[mi][ni] = (float4v){0.f, 0.f, 0.f, 0.f};

    gemm_core(A, sA, B, sB, 512, As, Bs, acc);

    u16 vals[4][4][4];
    if (z < 2) {
#pragma unroll
        for (int mi = 0; mi < 4; ++mi)
#pragma unroll
            for (int ni = 0; ni < 4; ++ni)
#pragma unroll
                for (int r = 0; r < 4; ++r)
                    vals[mi][ni][r] = f2bf_bits(acc[mi][ni][r] + bcol[ni]);
        u16* dst = (z ? kb : qb);
        store_tile_bf16(Ts[w], vals, lane15, quad,
                        dst + (size_t)(m0 + wm * 64) * sQK + n0 + wn * 64,
                        (size_t)sQK);
    } else {
#pragma unroll
        for (int mi = 0; mi < 4; ++mi)
#pragma unroll
            for (int ni = 0; ni < 4; ++ni)
#pragma unroll
                for (int r = 0; r < 4; ++r)
                    vals[mi][ni][r] = f2bf_bits(acc[mi][ni][r] + brow[mi][r]);
        const int b = n0 >> 11, tok0 = n0 & 2047;
        store_tile_bf16(Ts[w], vals, lane15, quad,
                        vt + (size_t)b * E_DIM * S_DIM +
                        (size_t)(m0 + wm * 64) * S_DIM + tok0 + wn * 64,
                        (size_t)S_DIM);
    }
}

// ---------------- gemmS: S = exp(masked(Q.K^T*scale)) + rowsum partials -----
__global__ __launch_bounds__(256) void gemmS(
    const u16* __restrict__ qb, const u16* __restrict__ kb, int sQK,
    const int* __restrict__ mask, const u32* __restrict__ bits, int bits_mode,
    const int* flagp, u16* sx_base, u16* sws_base, int nx,
    float* __restrict__ spart)
{
    __shared__ u16 As[4096] __attribute__((aligned(16)));
    __shared__ u16 Bs[4096] __attribute__((aligned(16)));
    __shared__ u32 Ms[128][4];
    __shared__ u16 Ts[4][64][40];
    __shared__ float Rred[128];
    GEMM_IDS();

    const int b = blockIdx.z, m0 = blockIdx.y * 128, ng = blockIdx.x;
    const int use_bits = (bits_mode == 2) ||
                         (bits_mode == 1 && !*(const volatile int*)flagp);
    const u16* A = qb + (size_t)(b * S_DIM + m0) * sQK;
    u16* Sb = (b < nx) ? (sx_base + (size_t)b * S_DIM * S_DIM)
                       : (sws_base + (size_t)(b - nx) * S_DIM * S_DIM);

    float rsum[4][4] = {};

    for (int nt = 0; nt < 2; ++nt) {
        const int n0 = ng * 256 + nt * 128;
        __syncthreads();
        if (use_bits && t < 128)
            gld16((const u16*)(bits + ((size_t)(b * S_DIM + m0 + t) * 64) + (n0 >> 5)),
                  (u16*)&Ms[t][0]);

        const u16* B = kb + (size_t)(b * S_DIM + n0) * sQK;
        float4v acc[4][4];
#pragma unroll
        for (int mi = 0; mi < 4; ++mi)
#pragma unroll
            for (int ni = 0; ni < 4; ++ni) acc[mi][ni] = (float4v){0.f, 0.f, 0.f, 0.f};

        gemm_core(A, sQK, B, sQK, 512, As, Bs, acc);

        u16 vals[4][4][4];
#pragma unroll
        for (int mi = 0; mi < 4; ++mi)
#pragma unroll
            for (int r = 0; r < 4; ++r) {
                const int rloc = wm * 64 + mi * 16 + quad * 4 + r;
                u32 w0 = 0, w1 = 0;
                int mkraw[4];
                if (use_bits) {
                    uint2 mw = *(const uint2*)&Ms[rloc][wn * 2];
                    w0 = mw.x; w1 = mw.y;
                } else {
#pragma unroll
                    for (int ni = 0; ni < 4; ++ni)
                        mkraw[ni] = mask[((size_t)b * S_DIM + m0 + rloc) * S_DIM +
                                         n0 + wn * 64 + ni * 16 + lane15];
                }
#pragma unroll
                for (int ni = 0; ni < 4; ++ni) {
                    int masked;
                    if (use_bits) {
                        const u32 word = (ni >> 1) ? w1 : w0;
                        masked = (word >> (((ni & 1) << 4) | lane15)) & 1;
                    } else masked = (mkraw[ni] > 0);
                    const float p = masked ? 0.f : __expf(acc[mi][ni][r] * SCALE);
                    const u16 hv = f2bf_bits(p);
                    vals[mi][ni][r] = hv;
                    rsum[mi][r] += bf2f(hv);
                }
            }
        store_tile_bf16(Ts[w], vals, lane15, quad,
                        Sb + (size_t)(m0 + wm * 64) * S_DIM + n0 + wn * 64,
                        (size_t)S_DIM);
    }

    // rowsum partials. Butterfly under FULL exec (R6 bug fix); result kept in
    // vred; wn0 publishes to Rred, wn1 adds its own and stores spart.
    float vred[4][4];
#pragma unroll
    for (int mi = 0; mi < 4; ++mi)
#pragma unroll
        for (int r = 0; r < 4; ++r) {
            float v = rsum[mi][r];
            v += __shfl_xor(v, 1, 64);
            v += __shfl_xor(v, 2, 64);
            v += __shfl_xor(v, 4, 64);
            v += __shfl_xor(v, 8, 64);
            vred[mi][r] = v;
            if (wn == 0 && lane15 == 0)
                Rred[wm * 64 + mi * 16 + quad * 4 + r] = v;
        }
    __syncthreads();
    if (wn == 1 && lane15 == 0) {
#pragma unroll
        for (int mi = 0; mi < 4; ++mi)
#pragma unroll
            for (int r = 0; r < 4; ++r) {
                const int rloc = wm * 64 + mi * 16 + quad * 4 + r;
                spart[((size_t)b * S_DIM + m0 + rloc) * 8 + ng] =
                    Rred[rloc] + vred[mi][r];
            }
    }
}

// ---------------- rowsum_reduce: rowtot = sum over 8 partials ----------------
__global__ __launch_bounds__(256) void rowsum_reduce(
    const float* __restrict__ spart, float* __restrict__ rowtot)
{
    const int i = blockIdx.x * 256 + threadIdx.x;      // 0..16383
    const float4 a = *(const float4*)(spart + (size_t)i * 8);
    const float4 b = *(const float4*)(spart + (size_t)i * 8 + 4);
    rowtot[i] = a.x + a.y + a.z + a.w + b.x + b.y + b.z + b.w;
}

// ---------------- gemmO: out = (S @ Vt) / rowtot ----------------
__global__ __launch_bounds__(256) void gemmO(
    const u16* sx_base, const u16* sws_base, int nx,
    const u16* __restrict__ vt, const float* __restrict__ rowtot,
    float* __restrict__ outp)
{
    __shared__ u16 As[4096] __attribute__((aligned(16)));
    __shared__ u16 Bs[4096] __attribute__((aligned(16)));
    GEMM_IDS();

    const int b = blockIdx.z;
    const int m0 = blockIdx.y * 128, n0 = blockIdx.x * 128;
    const u16* Sb = (b < nx) ? (sx_base + (size_t)b * S_DIM * S_DIM)
                             : (sws_base + (size_t)(b - nx) * S_DIM * S_DIM);
    const u16* A = Sb + (size_t)m0 * S_DIM;
    const u16* B = vt + ((size_t)b * E_DIM + n0) * S_DIM;

    float rt[4][4];
#pragma unroll
    for (int mi = 0; mi < 4; ++mi)
#pragma unroll
        for (int r = 0; r < 4; ++r)
            rt[mi][r] = rowtot[b * S_DIM + m0 + wm * 64 + mi * 16 + quad * 4 + r];

    float4v acc[4][4];
#pragma unroll
    for (int mi = 0; mi < 4; ++mi)
#pragma unroll
        for (int ni = 0; ni < 4; ++ni) acc[mi][ni] = (float4v){0.f, 0.f, 0.f, 0.f};

    gemm_core(A, S_DIM, B, S_DIM, S_DIM, As, Bs, acc);

#pragma unroll
    for (int mi = 0; mi < 4; ++mi)
#pragma unroll
        for (int r = 0; r < 4; ++r) {
            const int row = m0 + wm * 64 + mi * 16 + quad * 4 + r;
            const float inv = 1.f / rt[mi][r];
#pragma unroll
            for (int ni = 0; ni < 4; ++ni)
                outp[((size_t)b * S_DIM + row) * E_DIM + n0 + wn * 64 +
                     ni * 16 + lane15] = acc[mi][ni][r] * inv;
        }
}

extern "C" void kernel_launch(void* const* d_in, const int* in_sizes, int n_in,
                              void* d_out, int out_size, void* d_ws, size_t ws_size,
                              hipStream_t stream) {
    const void* x    = d_in[0];
    const int*  mask = (const int*)d_in[1];
    const void* wq   = d_in[2];
    const void* bq   = d_in[3];
    const void* wk   = d_in[4];
    const void* bk   = d_in[5];
    const void* wv   = d_in[6];
    const void* bv   = d_in[7];

    const size_t MB      = 1u << 20;
    const size_t QSZ_B   = (size_t)NROWS * E_DIM * 2;        // 16.8 MB
    const size_t S_PB_B  = (size_t)S_DIM * S_DIM * 2;        // 8.39 MB
    const size_t SPART_B = (size_t)NROWS * 8 * 4;            // 512 KB
    const size_t RTOT_B  = (size_t)NROWS * 4;                // 64 KB
    const size_t BITS_B  = (size_t)8 * S_DIM * 64 * 4;       // 4.2 MB
    const size_t BIG_NEED = 2 * MB + 3 * QSZ_B + SPART_B + RTOT_B +
                            8 * S_PB_B + BITS_B;             // ~124.3 MB

    u16* wb = (u16*)d_ws;
    const int* flagp = (const int*)((char*)d_ws + FLAG_BYTE);
    char* p = (char*)d_ws + 2 * MB;

    u16 *qb, *kb, *vtb, *sws; float *spart, *rowtot; u32* bits;
    u16* sx_base = (u16*)x;
    int sQK, nx, bits_mode;

    if (ws_size >= BIG_NEED) {
        qb  = (u16*)p;              p += QSZ_B;
        kb  = (u16*)p;              p += QSZ_B;
        vtb = (u16*)p;              p += QSZ_B;
        spart = (float*)p;          p += SPART_B;
        rowtot = (float*)p;         p += RTOT_B;
        sws = (u16*)p;              p += 8 * S_PB_B;
        bits = (u32*)p;
        sQK = 512; nx = 0; bits_mode = 2;
    } else {
        qb  = (u16*)d_out;
        kb  = (u16*)d_out + 512;
        vtb = (u16*)p;              p += QSZ_B;
        spart = (float*)p;          p += SPART_B;
        rowtot = (float*)p;         p += RTOT_B;
        sws = (u16*)p;
        bits = (u32*)((char*)x + 2 * S_PB_B);   // x back half (fp32 mode only)
        sQK = 1024; nx = 2; bits_mode = 1;
    }

    conv_w<<<dim3(128, 3), 256, 0, stream>>>(wq, wk, wv, bq, bk, bv, wb);
    conv_x<<<NROWS / 4, 256, 0, stream>>>((void*)x, flagp);

    proj_gemm<<<dim3(4, 128, 3), 256, 0, stream>>>(x, flagp, wb, qb, kb, sQK, vtb);

    mask_compress<<<4096, 256, 0, stream>>>(mask, bits, bits_mode, flagp);

    gemmS<<<dim3(8, 16, 8), 256, 0, stream>>>(qb, kb, sQK, mask, bits, bits_mode,
                                              flagp, sx_base, sws, nx, spart);

    rowsum_reduce<<<NROWS / 256, 256, 0, stream>>>(spart, rowtot);

    gemmO<<<dim3(4, 16, 8), 256, 0, stream>>>(sx_base, sws, nx, vtb, rowtot,
                                              (float*)d_out);
}